// Round 15
// baseline (85.216 us; speedup 1.0000x reference)
//
#include <hip/hip_runtime.h>
#include <hip/hip_fp8.h>

// out[i] = z[i] - COEFF*(2/N)*nf[i]*g[i],  g[i] = deg(i)*zr[i] - sum_{adj} zr[j],
// zr[j] = nf[j]*z[j].  adj counts both edge directions.
//
// 3-dispatch pipeline (fixed-stride bucket regions, no count/scan):
//  0) memset gfill (391 ints)
//  1) partition2 (+fused fp8 zr precompute): 256 blocks x 1024 thr (balanced,
//     16 waves/CU). LDS hist of node>>8, one global atomicAdd per
//     (block,bucket) reserves a run, then run writes (~32-rec / 128B runs).
//  2) bucket_sort_gather (1024 thr): block per 256-node bucket; LDS counting
//     sort of its region -> per-node adjacency; register fp8 gather with
//     4-way unrolled independent accumulators (MLP: ~4 outstanding random
//     loads/thread vs 1-2 with a single fadd chain) + fused finalize.

#define RANGE_SHIFT 8
#define RANGE 256
#define NPART 256
#define MAX_BUCKETS 512
#define CAP 9216
#define PBLK 1024
#define GBLK 1024

typedef float f32x2 __attribute__((ext_vector_type(2)));

static __device__ __forceinline__ unsigned char f2fp8(float f) {
    __hip_fp8_e4m3 h(f);
    return (unsigned char)h.__x;
}
static __device__ __forceinline__ float fp82f_sw(unsigned char b) {
    __hip_fp8_e4m3 h; h.__x = (__hip_fp8_storage_t)b; return (float)h;
}
static __device__ __forceinline__ float4 fp8x4_to_f32(unsigned v) {
#if __has_builtin(__builtin_amdgcn_cvt_pk_f32_fp8)
    f32x2 lo = __builtin_amdgcn_cvt_pk_f32_fp8(v, false);
    f32x2 hi = __builtin_amdgcn_cvt_pk_f32_fp8(v, true);
    return make_float4(lo[0], lo[1], hi[0], hi[1]);
#else
    return make_float4(fp82f_sw((unsigned char)(v & 0xFF)),
                       fp82f_sw((unsigned char)((v >> 8) & 0xFF)),
                       fp82f_sw((unsigned char)((v >> 16) & 0xFF)),
                       fp82f_sw((unsigned char)(v >> 24)));
#endif
}

// partition + fused zr8 precompute. 256 blocks x 1024 threads.
__global__ __launch_bounds__(PBLK) void partition2_kernel(const int* __restrict__ ei,
        int* __restrict__ gfill, unsigned* __restrict__ pack,
        int E, int ipb, int nbuck, int obits,
        const float4* __restrict__ z4, const float* __restrict__ nf,
        uchar4* __restrict__ zr8, int C, long totalP) {
    __shared__ int lcnt[MAX_BUCKETS];   // pass1 hist, then bump counter
    __shared__ int lbase[MAX_BUCKETS];  // reserved global run base
    for (int k = threadIdx.x; k < nbuck; k += PBLK) lcnt[k] = 0;
    __syncthreads();

    // fused precompute slice (independent; hides under hist latency)
    for (long t = (long)blockIdx.x * PBLK + threadIdx.x; t < totalP;
         t += (long)NPART * PBLK) {
        int node = (int)(t / C);
        float s = nf[node];
        float4 v = z4[t];
        uchar4 q;
        q.x = f2fp8(s * v.x); q.y = f2fp8(s * v.y);
        q.z = f2fp8(s * v.z); q.w = f2fp8(s * v.w);
        zr8[t] = q;
    }

    int twoE = 2 * E;
    int base = blockIdx.x * ipb;
    int endt = min(base + ipb, twoE);

    // Pass 1: LDS hist of own records (node column; L2-resident for pass 2).
    for (int t = base + threadIdx.x; t < endt; t += PBLK)
        atomicAdd(&lcnt[ei[t] >> RANGE_SHIFT], 1);
    __syncthreads();

    // Reserve one run per non-empty bucket (coalesced global atomics).
    for (int k = threadIdx.x; k < nbuck; k += PBLK) {
        int c = lcnt[k];
        lbase[k] = (c > 0) ? atomicAdd(&gfill[k], c) : 0;
        lcnt[k] = 0;                      // reuse as bump
    }
    __syncthreads();

    // Pass 2: place records into the reserved runs (~32-record / 128B runs).
    for (int t = base + threadIdx.x; t < endt; t += PBLK) {
        int node  = ei[t];
        int other = (t < E) ? ei[t + E] : ei[t - E];
        int bk = node >> RANGE_SHIFT;
        int pos = lbase[bk] + atomicAdd(&lcnt[bk], 1);
        if (pos < CAP)                    // 11-sigma guard (never expected)
            pack[(long)bk * CAP + pos] =
                ((unsigned)(node & (RANGE - 1)) << obits) | (unsigned)other;
    }
}

// Fused: in-LDS counting sort of own bucket region + fp8 register gather + finalize.
__global__ __launch_bounds__(GBLK) void bucket_sort_gather(
        const float4* __restrict__ z4, const unsigned* __restrict__ zr8,
        const float* __restrict__ nf, const unsigned* __restrict__ pack,
        const int* __restrict__ gfill, float4* __restrict__ out4,
        float scale, int N, int C, int nbuck, int obits) {
    __shared__ int adjl[CAP];
    __shared__ int lcnt[RANGE];
    __shared__ int lexc[RANGE];
    __shared__ int ldeg[RANGE];
    __shared__ int sbuf[RANGE];

    int b = blockIdx.x;
    long bstart = (long)b * CAP;
    int bsize = gfill[b];
    if (bsize > CAP) bsize = CAP;
    int tid = threadIdx.x;
    unsigned omask = (1u << obits) - 1u;
    int node0 = b << RANGE_SHIFT;

    if (tid < RANGE) lcnt[tid] = 0;
    __syncthreads();
    // Pass A: hist of node-locals over own region.
    for (int it = tid; it < bsize; it += GBLK)
        atomicAdd(&lcnt[pack[bstart + it] >> obits], 1);
    __syncthreads();
    // Exclusive scan of 256 counters (Hillis-Steele, barriers outside guards).
    if (tid < RANGE) sbuf[tid] = lcnt[tid];
    __syncthreads();
    for (int off = 1; off < RANGE; off <<= 1) {
        int v = 0, u = 0;
        if (tid < RANGE) { v = sbuf[tid]; if (tid >= off) u = sbuf[tid - off]; }
        __syncthreads();
        if (tid < RANGE) sbuf[tid] = v + u;
        __syncthreads();
    }
    if (tid < RANGE) {
        int inc = sbuf[tid], d = lcnt[tid];
        lexc[tid] = inc - d;
        ldeg[tid] = d;
        lcnt[tid] = 0;                    // reuse as bump
    }
    __syncthreads();
    // Pass B: place into per-node adjacency (L2-hot re-read).
    for (int it = tid; it < bsize; it += GBLK) {
        unsigned pk = pack[bstart + it];
        int il = (int)(pk >> obits);
        int r = atomicAdd(&lcnt[il], 1);
        adjl[lexc[il] + r] = (int)(pk & omask);
    }
    __syncthreads();
    // Pass C: register gather + fused finalize. RANGE*12 = 3072 tasks.
    // 4-way unrolled with independent accumulators for MLP/ILP.
    for (int task = tid; task < RANGE * 12; task += GBLK) {
        int nl = task / 12;
        int c  = task - nl * 12;
        int node = node0 + nl;
        if (node >= N) continue;
        int s  = lexc[nl];
        int dg = ldeg[nl];
        float4 s0 = make_float4(0.f, 0.f, 0.f, 0.f);
        float4 s1 = make_float4(0.f, 0.f, 0.f, 0.f);
        float4 s2 = make_float4(0.f, 0.f, 0.f, 0.f);
        float4 s3 = make_float4(0.f, 0.f, 0.f, 0.f);
        int k = 0;
        for (; k + 4 <= dg; k += 4) {
            int j0 = adjl[s + k + 0];
            int j1 = adjl[s + k + 1];
            int j2 = adjl[s + k + 2];
            int j3 = adjl[s + k + 3];
            unsigned q0 = zr8[(long)j0 * C + c];
            unsigned q1 = zr8[(long)j1 * C + c];
            unsigned q2 = zr8[(long)j2 * C + c];
            unsigned q3 = zr8[(long)j3 * C + c];
            float4 v0 = fp8x4_to_f32(q0);
            float4 v1 = fp8x4_to_f32(q1);
            float4 v2 = fp8x4_to_f32(q2);
            float4 v3 = fp8x4_to_f32(q3);
            s0.x += v0.x; s0.y += v0.y; s0.z += v0.z; s0.w += v0.w;
            s1.x += v1.x; s1.y += v1.y; s1.z += v1.z; s1.w += v1.w;
            s2.x += v2.x; s2.y += v2.y; s2.z += v2.z; s2.w += v2.w;
            s3.x += v3.x; s3.y += v3.y; s3.z += v3.z; s3.w += v3.w;
        }
        for (; k < dg; ++k) {
            int j = adjl[s + k];
            float4 v = fp8x4_to_f32(zr8[(long)j * C + c]);
            s0.x += v.x; s0.y += v.y; s0.z += v.z; s0.w += v.w;
        }
        float4 sum;
        sum.x = (s0.x + s1.x) + (s2.x + s3.x);
        sum.y = (s0.y + s1.y) + (s2.y + s3.y);
        sum.z = (s0.z + s1.z) + (s2.z + s3.z);
        sum.w = (s0.w + s1.w) + (s2.w + s3.w);
        float nfi = nf[node];
        float4 zi = z4[(long)node * C + c];
        float a   = scale * nfi;
        float dn  = (float)dg * nfi;
        float4 o;
        o.x = zi.x - a * (dn * zi.x - sum.x);
        o.y = zi.y - a * (dn * zi.y - sum.y);
        o.z = zi.z - a * (dn * zi.z - sum.z);
        o.w = zi.w - a * (dn * zi.w - sum.w);
        out4[(long)node * C + c] = o;
    }
}

// ---- fallback (round-1 atomic path) ----
__global__ void edge_scatter_kernel(const float* __restrict__ z, const int* __restrict__ ei,
                                    const float* __restrict__ nf, float* __restrict__ acc,
                                    int E, int D, long total) {
    long idx = (long)blockIdx.x * blockDim.x + threadIdx.x;
    if (idx >= total) return;
    int e = (int)(idx / D);
    int d = (int)(idx - (long)e * D);
    int r = ei[e];
    int c = ei[E + e];
    float diff = nf[r] * z[(long)r * D + d] - nf[c] * z[(long)c * D + d];
    atomicAdd(&acc[(long)r * D + d],  diff);
    atomicAdd(&acc[(long)c * D + d], -diff);
}
__global__ void finalize_kernel(const float* __restrict__ z, const float* __restrict__ nf,
                                float* __restrict__ out, float scale, int D, long total) {
    long i = (long)blockIdx.x * blockDim.x + threadIdx.x;
    if (i >= total) return;
    int node = (int)(i / D);
    out[i] = z[i] - scale * nf[node] * out[i];
}

extern "C" void kernel_launch(void* const* d_in, const int* in_sizes, int n_in,
                              void* d_out, int out_size, void* d_ws, size_t ws_size,
                              hipStream_t stream) {
    const float* z  = (const float*)d_in[0];
    const int*   ei = (const int*)d_in[2];
    const float* nf = (const float*)d_in[3];
    float* out = (float*)d_out;

    const int ND = in_sizes[0];
    const int Nn = in_sizes[3];
    const int D  = ND / Nn;
    const int E  = in_sizes[2] / 2;
    const int twoE = 2 * E;
    const float scale = 0.1f * 2.0f / (float)Nn;

    int obits = 1;
    while ((1 << obits) < Nn) obits++;
    const int nbuck = (Nn + RANGE - 1) >> RANGE_SHIFT;   // 391
    const int ipb = (twoE + NPART - 1) / NPART;          // 12500

    auto align_up = [](size_t x) { return (x + 255) & ~(size_t)255; };
    size_t off_gfill = 0;
    size_t off_pack  = off_gfill + align_up((size_t)nbuck * 4);
    size_t off_zr8   = off_pack  + align_up((size_t)nbuck * CAP * 4);
    size_t need      = off_zr8   + align_up((size_t)ND);

    // mean bucket size must leave >= ~10 sigma headroom under CAP
    bool ok = (D == 48) && (nbuck <= MAX_BUCKETS) && (obits + RANGE_SHIFT <= 32) &&
              (twoE / nbuck <= CAP - 1000) && (ws_size >= need);

    if (!ok) {
        hipMemsetAsync(out, 0, (size_t)ND * sizeof(float), stream);
        const long totalE = (long)E * D;
        edge_scatter_kernel<<<(int)((totalE + 255) / 256), 256, 0, stream>>>(
            z, ei, nf, out, E, D, totalE);
        finalize_kernel<<<(ND + 255) / 256, 256, 0, stream>>>(
            z, nf, out, scale, D, (long)ND);
        return;
    }

    char* w = (char*)d_ws;
    int*      gfill = (int*)(w + off_gfill);
    unsigned* pack  = (unsigned*)(w + off_pack);
    uchar4*   zr8   = (uchar4*)(w + off_zr8);

    const int C = D / 4;                 // 12
    long totalP = (long)Nn * C;

    hipMemsetAsync(gfill, 0, (size_t)nbuck * 4, stream);
    partition2_kernel<<<NPART, PBLK, 0, stream>>>(ei, gfill, pack, E, ipb, nbuck,
                                                  obits, (const float4*)z, nf, zr8, C, totalP);
    bucket_sort_gather<<<nbuck, GBLK, 0, stream>>>(
        (const float4*)z, (const unsigned*)zr8, nf, pack, gfill, (float4*)out,
        scale, Nn, C, nbuck, obits);
}

// Round 16
// 77.028 us; speedup vs baseline: 1.1063x; 1.1063x over previous
//
#include <hip/hip_runtime.h>
#include <hip/hip_fp8.h>

// out[i] = z[i] - COEFF*(2/N)*nf[i]*g[i],  g[i] = deg(i)*zr[i] - sum_{adj} zr[j],
// zr[j] = nf[j]*z[j].  adj counts both edge directions.
//
// 3-dispatch pipeline (fixed-stride bucket regions, no count/scan):
//  0) memset gfill (512 ints)
//  1) partition2 (+fused fp8 zr precompute): 256 blocks x 1024 thr (balanced).
//     LDS hist of node/PERB, one global atomicAdd per (block,bucket) reserves
//     a run, then run writes (~24-rec / 96B runs).
//  2) bucket_sort_gather (1024 thr): 512 blocks = EXACTLY 2 blocks/CU
//     (r14's 391 blocks left 135 CUs with 2x the work of the other 121 —
//     kernel ended at the slow CUs' pace). Block per 196-node bucket; LDS
//     counting sort -> per-node adjacency; simple register fp8 gather
//     (r15's 4-way unroll was null: VALU up, time flat) + fused finalize.

#define NBUCK 512
#define NPART 256
#define RMAX 256          // array sizing >= PERB
#define CAP 7168          // mean 6272 + 11 sigma
#define PBLK 1024
#define GBLK 1024

typedef float f32x2 __attribute__((ext_vector_type(2)));

static __device__ __forceinline__ unsigned char f2fp8(float f) {
    __hip_fp8_e4m3 h(f);
    return (unsigned char)h.__x;
}
static __device__ __forceinline__ float fp82f_sw(unsigned char b) {
    __hip_fp8_e4m3 h; h.__x = (__hip_fp8_storage_t)b; return (float)h;
}
static __device__ __forceinline__ float4 fp8x4_to_f32(unsigned v) {
#if __has_builtin(__builtin_amdgcn_cvt_pk_f32_fp8)
    f32x2 lo = __builtin_amdgcn_cvt_pk_f32_fp8(v, false);
    f32x2 hi = __builtin_amdgcn_cvt_pk_f32_fp8(v, true);
    return make_float4(lo[0], lo[1], hi[0], hi[1]);
#else
    return make_float4(fp82f_sw((unsigned char)(v & 0xFF)),
                       fp82f_sw((unsigned char)((v >> 8) & 0xFF)),
                       fp82f_sw((unsigned char)((v >> 16) & 0xFF)),
                       fp82f_sw((unsigned char)(v >> 24)));
#endif
}

// partition + fused zr8 precompute. 256 blocks x 1024 threads.
__global__ __launch_bounds__(PBLK) void partition2_kernel(const int* __restrict__ ei,
        int* __restrict__ gfill, unsigned* __restrict__ pack,
        int E, int ipb, int perb, int obits,
        const float4* __restrict__ z4, const float* __restrict__ nf,
        uchar4* __restrict__ zr8, int C, long totalP) {
    __shared__ int lcnt[NBUCK];   // pass1 hist, then bump counter
    __shared__ int lbase[NBUCK];  // reserved global run base
    for (int k = threadIdx.x; k < NBUCK; k += PBLK) lcnt[k] = 0;
    __syncthreads();

    // fused precompute slice (independent; hides under hist latency)
    for (long t = (long)blockIdx.x * PBLK + threadIdx.x; t < totalP;
         t += (long)NPART * PBLK) {
        int node = (int)(t / C);
        float s = nf[node];
        float4 v = z4[t];
        uchar4 q;
        q.x = f2fp8(s * v.x); q.y = f2fp8(s * v.y);
        q.z = f2fp8(s * v.z); q.w = f2fp8(s * v.w);
        zr8[t] = q;
    }

    int twoE = 2 * E;
    int base = blockIdx.x * ipb;
    int endt = min(base + ipb, twoE);

    // Pass 1: LDS hist of own records (node column; L2-resident for pass 2).
    for (int t = base + threadIdx.x; t < endt; t += PBLK)
        atomicAdd(&lcnt[ei[t] / perb], 1);
    __syncthreads();

    // Reserve one run per non-empty bucket (coalesced global atomics).
    for (int k = threadIdx.x; k < NBUCK; k += PBLK) {
        int c = lcnt[k];
        lbase[k] = (c > 0) ? atomicAdd(&gfill[k], c) : 0;
        lcnt[k] = 0;                      // reuse as bump
    }
    __syncthreads();

    // Pass 2: place records into the reserved runs (~24-record / 96B runs).
    for (int t = base + threadIdx.x; t < endt; t += PBLK) {
        int node  = ei[t];
        int other = (t < E) ? ei[t + E] : ei[t - E];
        int bk = node / perb;
        int il = node - bk * perb;
        int pos = lbase[bk] + atomicAdd(&lcnt[bk], 1);
        if (pos < CAP)                    // 11-sigma guard (never expected)
            pack[(long)bk * CAP + pos] = ((unsigned)il << obits) | (unsigned)other;
    }
}

// Fused: in-LDS counting sort of own bucket region + fp8 register gather + finalize.
__global__ __launch_bounds__(GBLK) void bucket_sort_gather(
        const float4* __restrict__ z4, const unsigned* __restrict__ zr8,
        const float* __restrict__ nf, const unsigned* __restrict__ pack,
        const int* __restrict__ gfill, float4* __restrict__ out4,
        float scale, int N, int C, int perb, int obits) {
    __shared__ int adjl[CAP];
    __shared__ int lcnt[RMAX];
    __shared__ int lexc[RMAX];
    __shared__ int ldeg[RMAX];
    __shared__ int sbuf[RMAX];

    int b = blockIdx.x;
    long bstart = (long)b * CAP;
    int bsize = gfill[b];
    if (bsize > CAP) bsize = CAP;
    int tid = threadIdx.x;
    unsigned omask = (1u << obits) - 1u;
    int node0 = b * perb;

    if (tid < RMAX) lcnt[tid] = 0;
    __syncthreads();
    // Pass A: hist of node-locals over own region.
    for (int it = tid; it < bsize; it += GBLK)
        atomicAdd(&lcnt[pack[bstart + it] >> obits], 1);
    __syncthreads();
    // Exclusive scan of RMAX counters (Hillis-Steele, barriers outside guards).
    if (tid < RMAX) sbuf[tid] = lcnt[tid];
    __syncthreads();
    for (int off = 1; off < RMAX; off <<= 1) {
        int v = 0, u = 0;
        if (tid < RMAX) { v = sbuf[tid]; if (tid >= off) u = sbuf[tid - off]; }
        __syncthreads();
        if (tid < RMAX) sbuf[tid] = v + u;
        __syncthreads();
    }
    if (tid < RMAX) {
        int inc = sbuf[tid], d = lcnt[tid];
        lexc[tid] = inc - d;
        ldeg[tid] = d;
        lcnt[tid] = 0;                    // reuse as bump
    }
    __syncthreads();
    // Pass B: place into per-node adjacency (L2-hot re-read).
    for (int it = tid; it < bsize; it += GBLK) {
        unsigned pk = pack[bstart + it];
        int il = (int)(pk >> obits);
        int r = atomicAdd(&lcnt[il], 1);
        adjl[lexc[il] + r] = (int)(pk & omask);
    }
    __syncthreads();
    // Pass C: register gather + fused finalize. perb*12 tasks.
    int ntask = perb * 12;
    for (int task = tid; task < ntask; task += GBLK) {
        int nl = task / 12;
        int c  = task - nl * 12;
        int node = node0 + nl;
        if (node >= N) continue;
        int s  = lexc[nl];
        int dg = ldeg[nl];
        float4 sum = make_float4(0.f, 0.f, 0.f, 0.f);
        #pragma unroll 4
        for (int k = 0; k < dg; ++k) {
            int j = adjl[s + k];
            float4 v = fp8x4_to_f32(zr8[(long)j * C + c]);
            sum.x += v.x; sum.y += v.y; sum.z += v.z; sum.w += v.w;
        }
        float nfi = nf[node];
        float4 zi = z4[(long)node * C + c];
        float a   = scale * nfi;
        float dn  = (float)dg * nfi;
        float4 o;
        o.x = zi.x - a * (dn * zi.x - sum.x);
        o.y = zi.y - a * (dn * zi.y - sum.y);
        o.z = zi.z - a * (dn * zi.z - sum.z);
        o.w = zi.w - a * (dn * zi.w - sum.w);
        out4[(long)node * C + c] = o;
    }
}

// ---- fallback (round-1 atomic path) ----
__global__ void edge_scatter_kernel(const float* __restrict__ z, const int* __restrict__ ei,
                                    const float* __restrict__ nf, float* __restrict__ acc,
                                    int E, int D, long total) {
    long idx = (long)blockIdx.x * blockDim.x + threadIdx.x;
    if (idx >= total) return;
    int e = (int)(idx / D);
    int d = (int)(idx - (long)e * D);
    int r = ei[e];
    int c = ei[E + e];
    float diff = nf[r] * z[(long)r * D + d] - nf[c] * z[(long)c * D + d];
    atomicAdd(&acc[(long)r * D + d],  diff);
    atomicAdd(&acc[(long)c * D + d], -diff);
}
__global__ void finalize_kernel(const float* __restrict__ z, const float* __restrict__ nf,
                                float* __restrict__ out, float scale, int D, long total) {
    long i = (long)blockIdx.x * blockDim.x + threadIdx.x;
    if (i >= total) return;
    int node = (int)(i / D);
    out[i] = z[i] - scale * nf[node] * out[i];
}

extern "C" void kernel_launch(void* const* d_in, const int* in_sizes, int n_in,
                              void* d_out, int out_size, void* d_ws, size_t ws_size,
                              hipStream_t stream) {
    const float* z  = (const float*)d_in[0];
    const int*   ei = (const int*)d_in[2];
    const float* nf = (const float*)d_in[3];
    float* out = (float*)d_out;

    const int ND = in_sizes[0];
    const int Nn = in_sizes[3];
    const int D  = ND / Nn;
    const int E  = in_sizes[2] / 2;
    const int twoE = 2 * E;
    const float scale = 0.1f * 2.0f / (float)Nn;

    int obits = 1;
    while ((1 << obits) < Nn) obits++;
    const int perb = (Nn + NBUCK - 1) / NBUCK;           // 196
    const int ipb  = (twoE + NPART - 1) / NPART;         // 12500

    auto align_up = [](size_t x) { return (x + 255) & ~(size_t)255; };
    size_t off_gfill = 0;
    size_t off_pack  = off_gfill + align_up((size_t)NBUCK * 4);
    size_t off_zr8   = off_pack  + align_up((size_t)NBUCK * CAP * 4);
    size_t need      = off_zr8   + align_up((size_t)ND);

    // mean bucket size must leave >= ~10 sigma headroom under CAP
    bool ok = (D == 48) && (perb <= RMAX) && (obits + 8 <= 32) &&
              (twoE / NBUCK <= CAP - 800) && (ws_size >= need);

    if (!ok) {
        hipMemsetAsync(out, 0, (size_t)ND * sizeof(float), stream);
        const long totalE = (long)E * D;
        edge_scatter_kernel<<<(int)((totalE + 255) / 256), 256, 0, stream>>>(
            z, ei, nf, out, E, D, totalE);
        finalize_kernel<<<(ND + 255) / 256, 256, 0, stream>>>(
            z, nf, out, scale, D, (long)ND);
        return;
    }

    char* w = (char*)d_ws;
    int*      gfill = (int*)(w + off_gfill);
    unsigned* pack  = (unsigned*)(w + off_pack);
    uchar4*   zr8   = (uchar4*)(w + off_zr8);

    const int C = D / 4;                 // 12
    long totalP = (long)Nn * C;

    hipMemsetAsync(gfill, 0, (size_t)NBUCK * 4, stream);
    partition2_kernel<<<NPART, PBLK, 0, stream>>>(ei, gfill, pack, E, ipb, perb,
                                                  obits, (const float4*)z, nf, zr8, C, totalP);
    bucket_sort_gather<<<NBUCK, GBLK, 0, stream>>>(
        (const float4*)z, (const unsigned*)zr8, nf, pack, gfill, (float4*)out,
        scale, Nn, C, perb, obits);
}